// Round 15
// baseline (504.317 us; speedup 1.0000x reference)
//
#include <hip/hip_runtime.h>
#include <hip/hip_bf16.h>
#include <cmath>

// Problem constants
#define Hdim 1024
#define Bdim 64
#define Sdim 1024

typedef __attribute__((ext_vector_type(4))) float f32x4;
typedef __attribute__((ext_vector_type(8))) short s16x8;
typedef __attribute__((ext_vector_type(4))) unsigned int u32x4;

static __device__ __forceinline__ unsigned short f2bf(float f) {
  unsigned int u = __builtin_bit_cast(unsigned int, f);
  unsigned int r = (u + 0x7fffu + ((u >> 16) & 1u)) >> 16;  // RNE (inputs are finite)
  return (unsigned short)r;
}

// cheap round-half-up: 2 ops; differs from RNE only at exact ties.
static __device__ __forceinline__ unsigned int f2bf_up(float f) {
  return (__builtin_bit_cast(unsigned int, f) + 0x8000u) >> 16;
}

static __device__ __forceinline__ float bf2f(unsigned short u) {
  return __builtin_bit_cast(float, (unsigned int)u << 16);
}

// fast tanh: 1 - 2/(1+exp2(x*2*log2e)); v_exp_f32 + v_rcp_f32, correct saturation.
#define TANH_C 2.885390081777927f

// ---------------- shared helpers ----------------

// Stage 64 rows x 1024 cols fp32 -> bf16 into LDS with XOR swizzle (proj only).
static __device__ __forceinline__ void stage_rows64(const float* __restrict__ src,
                                                    unsigned short* As, int tid) {
  #pragma unroll 4
  for (int i = 0; i < 32; ++i) {
    int c = tid + i * 256;
    int row = c >> 7;
    int k8 = (c & 127) << 3;
    const float4* p = reinterpret_cast<const float4*>(src + row * Hdim + k8);
    float4 a = p[0];
    float4 b = p[1];
    union { unsigned short us[8]; u32x4 v; } pk;
    pk.us[0] = f2bf(a.x); pk.us[1] = f2bf(a.y); pk.us[2] = f2bf(a.z); pk.us[3] = f2bf(a.w);
    pk.us[4] = f2bf(b.x); pk.us[5] = f2bf(b.y); pk.us[6] = f2bf(b.z); pk.us[7] = f2bf(b.w);
    int idx = row * Hdim + (k8 ^ ((row & 7) << 3));
    *reinterpret_cast<u32x4*>(&As[idx]) = pk.v;
  }
}

static __device__ __forceinline__ s16x8 lda_full(const unsigned short* As, int row, int k) {
  int idx = row * Hdim + (k ^ ((row & 7) << 3));
  return *reinterpret_cast<const s16x8*>(&As[idx]);
}

static __device__ __forceinline__ s16x8 ldb_g(const unsigned short* __restrict__ Wb,
                                              const float* __restrict__ Wf,
                                              int use_bf, int o, int k) {
  if (use_bf) {
    return *reinterpret_cast<const s16x8*>(&Wb[o * Hdim + k]);
  } else {
    const float4* p = reinterpret_cast<const float4*>(Wf + o * Hdim + k);
    float4 a = p[0];
    float4 b = p[1];
    union { unsigned short us[8]; s16x8 v; } pk;
    pk.us[0] = f2bf(a.x); pk.us[1] = f2bf(a.y); pk.us[2] = f2bf(a.z); pk.us[3] = f2bf(a.w);
    pk.us[4] = f2bf(b.x); pk.us[5] = f2bf(b.y); pk.us[6] = f2bf(b.z); pk.us[7] = f2bf(b.w);
    return pk.v;
  }
}

// Cast fp32 -> bf16, 8 elems/thread (W1/W2 only; 512 blocks).
__global__ void cast_bf16_kernel(const float* __restrict__ src,
                                 unsigned short* __restrict__ dst) {
  int i = blockIdx.x * 256 + threadIdx.x;
  const f32x4* p = reinterpret_cast<const f32x4*>(src) + i * 2;
  f32x4 a = p[0];
  f32x4 b = p[1];
  union { unsigned short us[8]; u32x4 v; } pk;
  pk.us[0] = f2bf(a[0]); pk.us[1] = f2bf(a[1]); pk.us[2] = f2bf(a[2]); pk.us[3] = f2bf(a[3]);
  pk.us[4] = f2bf(b[0]); pk.us[5] = f2bf(b[1]); pk.us[6] = f2bf(b[2]); pk.us[7] = f2bf(b[3]);
  *reinterpret_cast<u32x4*>(dst + i * 8) = pk.v;
}

// dh_proj[b][o] = sum_h dh[b][h] * W1[o][h]. Grid: 64 blocks (16-wide o-tile each).
__global__ __launch_bounds__(256, 1) void proj_kernel(
    const float* __restrict__ dh, const float* __restrict__ W1f,
    const unsigned short* __restrict__ W1b, float* __restrict__ out, int use_bf) {
  __shared__ unsigned short As[64 * Hdim];
  int tid = threadIdx.x;
  stage_rows64(dh, As, tid);
  __syncthreads();
  int w = tid >> 6, lane = tid & 63;
  int lo = lane & 15, hi = lane >> 4;
  int o = blockIdx.x * 16 + lo;
  f32x4 acc = {0.f, 0.f, 0.f, 0.f};
  for (int k0 = 0; k0 < Hdim; k0 += 32) {
    int k = k0 + hi * 8;
    s16x8 bfrag = ldb_g(W1b, W1f, use_bf, o, k);
    s16x8 afrag = lda_full(As, w * 16 + lo, k);
    acc = __builtin_amdgcn_mfma_f32_16x16x32_bf16(afrag, bfrag, acc, 0, 0, 0);
  }
  #pragma unroll
  for (int r = 0; r < 4; ++r)
    out[(w * 16 + hi * 4 + r) * Hdim + o] = acc[r];
}

// ---------------- score kernel (fast path): 256x128 FUSED fp32->bf16 A ----------
// R13 geometry (proven benign: 4Mx2N waves, 48 KB LDS, 2 blocks/CU, simple
// {sync; stage; vmcnt(0); sync; compute} loop) + A converted in-kernel from
// fp32 enc — eliminates the separate 61us cast-enc pass. Per K-tile:
//   sync; issue B gload_lds(2); issue A fp32 loads half0 (4xdwordx4/thr);
//   vmcnt(0); pack(f2bf_up)+ds_write half0 (+encb nt-store if np==0);
//   issue A half1; vmcnt(0); pack+write half1; sync; compute.
// Two sub-phases keep ar at 16 VGPR (total <=128 -> 2 blocks/CU holds).
// ds_write swizzle: chunk c at byte row*128 + ((c*16) ^ ((row&7)*16)) — the
// same involution the compute reads use; write pattern is 2-way (free).
#define SBM 256
#define SBN 128
#define SBK 64

__global__ __launch_bounds__(512, 4) void score_fused_kernel(
    const float* __restrict__ enc,            // [B*S][H] fp32
    const unsigned short* __restrict__ W2b,   // [H][H] bf16
    const float* __restrict__ dhp, const float* __restrict__ v,
    float* __restrict__ scores,
    unsigned short* __restrict__ encb) {      // bf16 side-product for context
  __shared__ unsigned short As[SBM * SBK];  // 32 KB
  __shared__ unsigned short Bs[SBN * SBK];  // 16 KB (48 KB total)
  int tid = threadIdx.x;   // 0..511
  int bid = blockIdx.x;    // 0..2047
  int swz = (bid & 7) * 256 + (bid >> 3);  // XCD-chunked, bijective (2048%8==0)
  int mp = swz >> 3;                 // [0,256) A-panel
  int np = swz & 7;                  // [0,8)   o-panel
  int row0 = mp * SBM;
  int b = row0 >> 10;
  int w = tid >> 6, lane = tid & 63;
  int wr = w >> 1, wc = w & 1;       // 4M x 2N wave grid
  int lo = lane & 15, hi = lane >> 4;
  int xorv = (lo & 7) << 4;          // read-side byte XOR
  int wr_encb = (np == 0);

  // B staging sources (source-preswizzled chunks)
  int srow = tid >> 3;
  int gcB = (tid & 7) ^ (srow & 7);
  const unsigned short* gB0 = W2b + (size_t)(np * SBN + srow) * Hdim + gcB * 8;

  // A staging: thread handles row arow, 32 floats at column khalf*32
  int arow = tid >> 1;               // 0..255
  int khalf = tid & 1;
  const float* gA = enc + (size_t)(row0 + arow) * Hdim + khalf * 32;
  unsigned short* encb_dst0 = encb + (size_t)(row0 + arow) * Hdim + khalf * 32;
  unsigned short* As_row = &As[arow * 64];
  int arow7 = (arow & 7) * 16;       // byte XOR for the write side

  f32x4 acc[4][4] = {};  // [m][n] -- wave-tile 64x64

  for (int t = 0; t < 16; ++t) {
    __syncthreads();
    // B: 2 x global_load_lds width-16
    #pragma unroll
    for (int g = 0; g < 2; ++g) {
      __builtin_amdgcn_global_load_lds(
          (const __attribute__((address_space(1))) unsigned int*)(gB0 + (size_t)g * 64 * Hdim + t * SBK),
          (__attribute__((address_space(3))) unsigned int*)(&Bs[(g * 512 + w * 64) * 8]), 16, 0, 0);
    }
    // A: two sub-phases of 4 x dwordx4 -> pack -> swizzled ds_write (+encb)
    #pragma unroll
    for (int ph = 0; ph < 2; ++ph) {
      f32x4 ar[4];
      #pragma unroll
      for (int j = 0; j < 4; ++j)
        ar[j] = *reinterpret_cast<const f32x4*>(gA + t * SBK + ph * 16 + j * 4);
      asm volatile("s_waitcnt vmcnt(0)" ::: "memory");
      #pragma unroll
      for (int j2 = 0; j2 < 2; ++j2) {
        u32x4 pk;
        pk[0] = f2bf_up(ar[j2*2][0])   | (f2bf_up(ar[j2*2][1]) << 16);
        pk[1] = f2bf_up(ar[j2*2][2])   | (f2bf_up(ar[j2*2][3]) << 16);
        pk[2] = f2bf_up(ar[j2*2+1][0]) | (f2bf_up(ar[j2*2+1][1]) << 16);
        pk[3] = f2bf_up(ar[j2*2+1][2]) | (f2bf_up(ar[j2*2+1][3]) << 16);
        int c = khalf * 4 + ph * 2 + j2;          // 16B chunk index 0..7
        *reinterpret_cast<u32x4*>(
            reinterpret_cast<char*>(As_row) + ((c * 16) ^ arow7)) = pk;
        if (wr_encb) {
          __builtin_nontemporal_store(pk, reinterpret_cast<u32x4*>(
              encb_dst0 + t * SBK + ph * 16 + j2 * 8));
        }
      }
    }
    __syncthreads();  // waits lgkm (ds_writes) + vm (B gload_lds already drained)

    const char* Ab = (const char*)As;
    const char* Bb = (const char*)Bs;
    #pragma unroll
    for (int ks = 0; ks < 2; ++ks) {
      int kb = (ks * 32 + hi * 8) * 2;  // byte offset within 128B row
      s16x8 af[4], bf[4];
      #pragma unroll
      for (int m = 0; m < 4; ++m) {
        int row = wr * 64 + m * 16 + lo;
        af[m] = *reinterpret_cast<const s16x8*>(Ab + row * 128 + (kb ^ xorv));
      }
      #pragma unroll
      for (int n = 0; n < 4; ++n) {
        int row = wc * 64 + n * 16 + lo;
        bf[n] = *reinterpret_cast<const s16x8*>(Bb + row * 128 + (kb ^ xorv));
      }
      #pragma unroll
      for (int m = 0; m < 4; ++m)
        #pragma unroll
        for (int n = 0; n < 4; ++n)
          acc[m][n] = __builtin_amdgcn_mfma_f32_16x16x32_bf16(af[m], bf[n], acc[m][n], 0, 0, 0);
    }
  }

  // epilogue: fast tanh(energy + dh_proj)*v summed over this block's 128 o's
  float psum[4][4] = {};  // [m][r]
  #pragma unroll
  for (int n = 0; n < 4; ++n) {
    int o = np * SBN + wc * 64 + n * 16 + lo;
    float dv = dhp[b * Hdim + o];
    float vv = v[o];
    float vv2 = 2.f * vv;
    #pragma unroll
    for (int m = 0; m < 4; ++m)
      #pragma unroll
      for (int r = 0; r < 4; ++r) {
        float x = acc[m][n][r] + dv;
        float e2 = __builtin_amdgcn_exp2f(x * TANH_C);
        float rc = __builtin_amdgcn_rcpf(1.f + e2);
        psum[m][r] += vv - vv2 * rc;  // v * tanh(x)
      }
  }
  #pragma unroll
  for (int mask = 1; mask < 16; mask <<= 1)
    #pragma unroll
    for (int m = 0; m < 4; ++m)
      #pragma unroll
      for (int r = 0; r < 4; ++r)
        psum[m][r] += __shfl_xor(psum[m][r], mask, 64);
  if (lo == 0) {
    #pragma unroll
    for (int m = 0; m < 4; ++m)
      #pragma unroll
      for (int r = 0; r < 4; ++r)
        atomicAdd(&scores[row0 + wr * 64 + m * 16 + hi * 4 + r], psum[m][r]);
  }
}

// ---------------- score kernel (fallback): reg-staged fp32 path ----------------
#define BKt 64

__global__ __launch_bounds__(256, 3) void score_kernel(
    const float* __restrict__ enc, const float* __restrict__ W2f,
    const unsigned short* __restrict__ W2b, const float* __restrict__ dhp,
    const float* __restrict__ v, float* __restrict__ scores, int use_bf) {
  __shared__ unsigned short As[64 * BKt];
  int tid = threadIdx.x;
  int bid = blockIdx.x;
  int f = (bid & 7) * 512 + (bid >> 3);
  int rg = f >> 2;
  int oc = f & 3;
  int row0 = rg * 64;
  int b = row0 >> 10;
  int w = tid >> 6, lane = tid & 63;
  int lo = lane & 15, hi = lane >> 4;
  int n0 = oc * 256 + w * 64;

  const unsigned short* pB[4];
  const float* pBf[4];
  #pragma unroll
  for (int n = 0; n < 4; ++n) {
    int o = n0 + n * 16 + lo;
    pB[n]  = W2b + (size_t)o * Hdim + hi * 8;
    pBf[n] = W2f + (size_t)o * Hdim + hi * 8;
  }

  f32x4 acc[4][4] = {};

  for (int t = 0; t < 16; ++t) {
    int k0 = t * BKt;
    __syncthreads();
    #pragma unroll
    for (int cc = 0; cc < 2; ++cc) {
      int c = tid + cc * 256;
      int row = c >> 3;
      int j = c & 7;
      const float4* p = reinterpret_cast<const float4*>(
          enc + (size_t)(row0 + row) * Hdim + k0 + j * 8);
      float4 a = p[0];
      float4 bb = p[1];
      union { unsigned short us[8]; u32x4 v4; } pk;
      pk.us[0] = f2bf(a.x);  pk.us[1] = f2bf(a.y);  pk.us[2] = f2bf(a.z);  pk.us[3] = f2bf(a.w);
      pk.us[4] = f2bf(bb.x); pk.us[5] = f2bf(bb.y); pk.us[6] = f2bf(bb.z); pk.us[7] = f2bf(bb.w);
      int idx = row * BKt + ((j * 8) ^ ((row & 7) << 3));
      *reinterpret_cast<u32x4*>(&As[idx]) = pk.v4;
    }
    __syncthreads();

    #pragma unroll
    for (int ks = 0; ks < 2; ++ks) {
      s16x8 bfrag[4];
      #pragma unroll
      for (int n = 0; n < 4; ++n) {
        if (use_bf) {
          bfrag[n] = *reinterpret_cast<const s16x8*>(pB[n] + ks * 32);
        } else {
          const float4* p = reinterpret_cast<const float4*>(pBf[n] + ks * 32);
          float4 a = p[0];
          float4 bb = p[1];
          union { unsigned short us[8]; s16x8 v4; } pk;
          pk.us[0] = f2bf(a.x);  pk.us[1] = f2bf(a.y);  pk.us[2] = f2bf(a.z);  pk.us[3] = f2bf(a.w);
          pk.us[4] = f2bf(bb.x); pk.us[5] = f2bf(bb.y); pk.us[6] = f2bf(bb.z); pk.us[7] = f2bf(bb.w);
          bfrag[n] = pk.v4;
        }
      }
      #pragma unroll
      for (int m = 0; m < 4; ++m) {
        int kk = ks * 32 + hi * 8;
        s16x8 afrag = *reinterpret_cast<const s16x8*>(
            &As[(m * 16 + lo) * BKt + (kk ^ ((lo & 7) << 3))]);
        #pragma unroll
        for (int n = 0; n < 4; ++n)
          acc[m][n] = __builtin_amdgcn_mfma_f32_16x16x32_bf16(afrag, bfrag[n], acc[m][n], 0, 0, 0);
      }
    }
    #pragma unroll
    for (int n = 0; n < 4; ++n) { pB[n] += BKt; pBf[n] += BKt; }
  }

  float psum[4][4] = {};
  #pragma unroll
  for (int n = 0; n < 4; ++n) {
    int o = n0 + n * 16 + lo;
    float dv = dhp[b * Hdim + o];
    float vv = v[o];
    float vv2 = 2.f * vv;
    #pragma unroll
    for (int m = 0; m < 4; ++m)
      #pragma unroll
      for (int r = 0; r < 4; ++r) {
        float x = acc[m][n][r] + dv;
        float e2 = __builtin_amdgcn_exp2f(x * TANH_C);
        float rc = __builtin_amdgcn_rcpf(1.f + e2);
        psum[m][r] += vv - vv2 * rc;
      }
  }
  #pragma unroll
  for (int mask = 1; mask < 16; mask <<= 1)
    #pragma unroll
    for (int m = 0; m < 4; ++m)
      #pragma unroll
      for (int r = 0; r < 4; ++r)
        psum[m][r] += __shfl_xor(psum[m][r], mask, 64);
  if (lo == 0) {
    #pragma unroll
    for (int m = 0; m < 4; ++m)
      #pragma unroll
      for (int r = 0; r < 4; ++r)
        atomicAdd(&scores[row0 + m * 16 + hi * 4 + r], psum[m][r]);
  }
}

// In-place softmax over S=1024 per batch row. Grid: 64 blocks x 256 threads.
__global__ __launch_bounds__(256, 1) void softmax_kernel(float* __restrict__ attn) {
  __shared__ float redm[4];
  __shared__ float reds[4];
  int b = blockIdx.x, tid = threadIdx.x;
  float4 x = *reinterpret_cast<float4*>(attn + b * Sdim + tid * 4);
  float m = fmaxf(fmaxf(x.x, x.y), fmaxf(x.z, x.w));
  #pragma unroll
  for (int mask = 1; mask < 64; mask <<= 1) m = fmaxf(m, __shfl_xor(m, mask, 64));
  if ((tid & 63) == 0) redm[tid >> 6] = m;
  __syncthreads();
  m = fmaxf(fmaxf(redm[0], redm[1]), fmaxf(redm[2], redm[3]));
  float4 e;
  e.x = expf(x.x - m); e.y = expf(x.y - m); e.z = expf(x.z - m); e.w = expf(x.w - m);
  float s = e.x + e.y + e.z + e.w;
  #pragma unroll
  for (int mask = 1; mask < 64; mask <<= 1) s += __shfl_xor(s, mask, 64);
  if ((tid & 63) == 0) reds[tid >> 6] = s;
  __syncthreads();
  s = reds[0] + reds[1] + reds[2] + reds[3];
  float inv = 1.f / s;
  e.x *= inv; e.y *= inv; e.z *= inv; e.w *= inv;
  *reinterpret_cast<float4*>(attn + b * Sdim + tid * 4) = e;
}

// context[b][h] = sum_s attn[b][s] * enc[b][s][h], bf16 enc path.
// Grid: 1024 blocks (64 b x 16 s-chunks of 64).
__global__ __launch_bounds__(256, 1) void context_bf_kernel(
    const unsigned short* __restrict__ encb, const float* __restrict__ attn,
    float* __restrict__ ctx) {
  int b = blockIdx.x >> 4;
  int chunk = blockIdx.x & 15;
  int tid = threadIdx.x;
  int h0 = tid * 4;
  const unsigned short* ebase = encb + ((size_t)(b * Sdim + chunk * 64)) * Hdim + h0;
  const float* abase = attn + b * Sdim + chunk * 64;
  float4 acc = {0.f, 0.f, 0.f, 0.f};
  #pragma unroll 4
  for (int s = 0; s < 64; ++s) {
    float wgt = abase[s];
    ushort4 ev = *reinterpret_cast<const ushort4*>(ebase + (size_t)s * Hdim);
    acc.x += wgt * bf2f(ev.x);
    acc.y += wgt * bf2f(ev.y);
    acc.z += wgt * bf2f(ev.z);
    acc.w += wgt * bf2f(ev.w);
  }
  float* c = ctx + b * Hdim + h0;
  atomicAdd(c + 0, acc.x);
  atomicAdd(c + 1, acc.y);
  atomicAdd(c + 2, acc.z);
  atomicAdd(c + 3, acc.w);
}

// fp32 fallback context. Grid: 512 blocks (64 b x 8 s-chunks of 128).
__global__ __launch_bounds__(256, 1) void context_kernel(
    const float* __restrict__ enc, const float* __restrict__ attn,
    float* __restrict__ ctx) {
  int b = blockIdx.x >> 3;
  int chunk = blockIdx.x & 7;
  int tid = threadIdx.x;
  int h0 = tid * 4;
  const float* ebase = enc + ((size_t)(b * Sdim + chunk * 128)) * Hdim + h0;
  const float* abase = attn + b * Sdim + chunk * 128;
  float4 acc = {0.f, 0.f, 0.f, 0.f};
  #pragma unroll 4
  for (int s = 0; s < 128; ++s) {
    float wgt = abase[s];
    float4 ev = *reinterpret_cast<const float4*>(ebase + (size_t)s * Hdim);
    acc.x += wgt * ev.x; acc.y += wgt * ev.y; acc.z += wgt * ev.z; acc.w += wgt * ev.w;
  }
  float* c = ctx + b * Hdim + h0;
  atomicAdd(c + 0, acc.x);
  atomicAdd(c + 1, acc.y);
  atomicAdd(c + 2, acc.z);
  atomicAdd(c + 3, acc.w);
}

extern "C" void kernel_launch(void* const* d_in, const int* in_sizes, int n_in,
                              void* d_out, int out_size, void* d_ws, size_t ws_size,
                              hipStream_t stream) {
  const float* dh  = (const float*)d_in[0];  // [64,1024]
  const float* enc = (const float*)d_in[1];  // [64,1024,1024]
  const float* W1  = (const float*)d_in[2];  // [1024,1024]
  const float* W2  = (const float*)d_in[3];  // [1024,1024]
  const float* v   = (const float*)d_in[4];  // [1024]
  float* out_ctx  = (float*)d_out;           // [64,1024]
  float* out_attn = out_ctx + Bdim * Hdim;   // [64,1024]

  int use_bf = (ws_size >= 4ull * 1024 * 1024) ? 1 : 0;
  // fast path needs W1b+W2b (4 MB) + encb (128 MB)
  int big_ws = (ws_size >= 133ull * 1024 * 1024 && use_bf) ? 1 : 0;
  unsigned short* W1b  = (unsigned short*)d_ws;
  unsigned short* W2b  = W1b + 1024 * 1024;
  unsigned short* encb = W2b + 1024 * 1024;

  if (use_bf) {
    cast_bf16_kernel<<<512, 256, 0, stream>>>(W1, W1b);
    cast_bf16_kernel<<<512, 256, 0, stream>>>(W2, W2b);
  }

  // dh_proj parked in out_ctx (region is free until the context pass)
  proj_kernel<<<64, 256, 0, stream>>>(dh, W1, W1b, out_ctx, use_bf);

  // raw scores accumulate into zeroed out_attn; fast path also emits encb (bf16)
  hipMemsetAsync(out_attn, 0, (size_t)Bdim * Sdim * sizeof(float), stream);
  if (big_ws) {
    score_fused_kernel<<<2048, 512, 0, stream>>>(enc, W2b, out_ctx, v, out_attn, encb);
  } else {
    score_kernel<<<4096, 256, 0, stream>>>(enc, W2, W2b, out_ctx, v, out_attn, use_bf);
  }

  softmax_kernel<<<Bdim, 256, 0, stream>>>(out_attn);

  hipMemsetAsync(out_ctx, 0, (size_t)Bdim * Hdim * sizeof(float), stream);
  if (big_ws) {
    context_bf_kernel<<<1024, 256, 0, stream>>>(encb, out_attn, out_ctx);
  } else {
    context_kernel<<<512, 256, 0, stream>>>(enc, out_attn, out_ctx);
  }
}

// Round 16
// 289.542 us; speedup vs baseline: 1.7418x; 1.7418x over previous
//
#include <hip/hip_runtime.h>
#include <hip/hip_bf16.h>
#include <cmath>

// Problem constants
#define Hdim 1024
#define Bdim 64
#define Sdim 1024

typedef __attribute__((ext_vector_type(4))) float f32x4;
typedef __attribute__((ext_vector_type(8))) short s16x8;
typedef __attribute__((ext_vector_type(4))) unsigned int u32x4;

static __device__ __forceinline__ unsigned short f2bf(float f) {
  unsigned int u = __builtin_bit_cast(unsigned int, f);
  unsigned int r = (u + 0x7fffu + ((u >> 16) & 1u)) >> 16;  // RNE (inputs are finite)
  return (unsigned short)r;
}

static __device__ __forceinline__ float bf2f(unsigned short u) {
  return __builtin_bit_cast(float, (unsigned int)u << 16);
}

// fast tanh: 1 - 2/(1+exp2(x*2*log2e)); v_exp_f32 + v_rcp_f32, correct saturation.
#define TANH_C 2.885390081777927f

// ---------------- shared helpers ----------------

// Stage 64 rows x 1024 cols fp32 -> bf16 into LDS with XOR swizzle.
static __device__ __forceinline__ void stage_rows64(const float* __restrict__ src,
                                                    unsigned short* As, int tid) {
  #pragma unroll 4
  for (int i = 0; i < 32; ++i) {
    int c = tid + i * 256;
    int row = c >> 7;
    int k8 = (c & 127) << 3;
    const float4* p = reinterpret_cast<const float4*>(src + row * Hdim + k8);
    float4 a = p[0];
    float4 b = p[1];
    union { unsigned short us[8]; u32x4 v; } pk;
    pk.us[0] = f2bf(a.x); pk.us[1] = f2bf(a.y); pk.us[2] = f2bf(a.z); pk.us[3] = f2bf(a.w);
    pk.us[4] = f2bf(b.x); pk.us[5] = f2bf(b.y); pk.us[6] = f2bf(b.z); pk.us[7] = f2bf(b.w);
    int idx = row * Hdim + (k8 ^ ((row & 7) << 3));
    *reinterpret_cast<u32x4*>(&As[idx]) = pk.v;
  }
}

static __device__ __forceinline__ s16x8 lda_full(const unsigned short* As, int row, int k) {
  int idx = row * Hdim + (k ^ ((row & 7) << 3));
  return *reinterpret_cast<const s16x8*>(&As[idx]);
}

static __device__ __forceinline__ s16x8 ldb_g(const unsigned short* __restrict__ Wb,
                                              const float* __restrict__ Wf,
                                              int use_bf, int o, int k) {
  if (use_bf) {
    return *reinterpret_cast<const s16x8*>(&Wb[o * Hdim + k]);
  } else {
    const float4* p = reinterpret_cast<const float4*>(Wf + o * Hdim + k);
    float4 a = p[0];
    float4 b = p[1];
    union { unsigned short us[8]; s16x8 v; } pk;
    pk.us[0] = f2bf(a.x); pk.us[1] = f2bf(a.y); pk.us[2] = f2bf(a.z); pk.us[3] = f2bf(a.w);
    pk.us[4] = f2bf(b.x); pk.us[5] = f2bf(b.y); pk.us[6] = f2bf(b.z); pk.us[7] = f2bf(b.w);
    return pk.v;
  }
}

// Cast fp32 -> bf16, 8 elems/thread (grid-sized by caller).
// NONTEMPORAL source reads (keep freshly-written bf16 L3-resident).
__global__ void cast_bf16_kernel(const float* __restrict__ src,
                                 unsigned short* __restrict__ dst) {
  int i = blockIdx.x * 256 + threadIdx.x;
  const f32x4* p = reinterpret_cast<const f32x4*>(src) + i * 2;
  f32x4 a = __builtin_nontemporal_load(p);
  f32x4 b = __builtin_nontemporal_load(p + 1);
  union { unsigned short us[8]; u32x4 v; } pk;
  pk.us[0] = f2bf(a[0]); pk.us[1] = f2bf(a[1]); pk.us[2] = f2bf(a[2]); pk.us[3] = f2bf(a[3]);
  pk.us[4] = f2bf(b[0]); pk.us[5] = f2bf(b[1]); pk.us[6] = f2bf(b[2]); pk.us[7] = f2bf(b[3]);
  *reinterpret_cast<u32x4*>(dst + i * 8) = pk.v;
}

// dh_proj[b][o] = sum_h dh[b][h] * W1[o][h]. Grid: 64 blocks (16-wide o-tile each).
__global__ __launch_bounds__(256, 1) void proj_kernel(
    const float* __restrict__ dh, const float* __restrict__ W1f,
    const unsigned short* __restrict__ W1b, float* __restrict__ out, int use_bf) {
  __shared__ unsigned short As[64 * Hdim];
  int tid = threadIdx.x;
  stage_rows64(dh, As, tid);
  __syncthreads();
  int w = tid >> 6, lane = tid & 63;
  int lo = lane & 15, hi = lane >> 4;
  int o = blockIdx.x * 16 + lo;
  f32x4 acc = {0.f, 0.f, 0.f, 0.f};
  for (int k0 = 0; k0 < Hdim; k0 += 32) {
    int k = k0 + hi * 8;
    s16x8 bfrag = ldb_g(W1b, W1f, use_bf, o, k);
    s16x8 afrag = lda_full(As, w * 16 + lo, k);
    acc = __builtin_amdgcn_mfma_f32_16x16x32_bf16(afrag, bfrag, acc, 0, 0, 0);
  }
  #pragma unroll
  for (int r = 0; r < 4; ++r)
    out[(w * 16 + hi * 4 + r) * Hdim + o] = acc[r];
}

// ---------------- score kernel (fast path): 256x256 8-phase counted-vmcnt ----------------
// Best-measured configuration (R8/R9: 176 us, MfmaUtil ~33%). BM=BN=256, BK=64,
// 8 waves (2M x 4N), wave-tile 128x64 as 2x2 quadrants. A/B double-buffered
// (128 KB). Phase: {2 gload_lds stages, snake ds_reads, vmcnt(4), barrier,
// setprio MFMA}. Stage-pair order matches snake read order.
#define SBM 256
#define SBN 256
#define SBK 64

__global__ __launch_bounds__(512, 1) void score_mfma_kernel(
    const unsigned short* __restrict__ encb,  // [B*S][H] bf16
    const unsigned short* __restrict__ W2b,   // [H][H] bf16
    const float* __restrict__ dhp, const float* __restrict__ v,
    float* __restrict__ scores) {
  __shared__ unsigned short As[2][SBM * SBK];  // 2 x 32 KB
  __shared__ unsigned short Bs[2][SBN * SBK];  // 2 x 32 KB (128 KB total)
  int tid = threadIdx.x;   // 0..511
  int bid = blockIdx.x;    // 0..1023
  int swz = (bid & 7) * 128 + (bid >> 3);  // XCD-chunked, bijective
  int mp = swz >> 2;                 // [0,256) A-panel
  int np = swz & 3;                  // [0,4)   o-panel
  int row0 = mp * SBM;
  int b = row0 >> 10;
  int w = tid >> 6, lane = tid & 63;
  int wr = w >> 2, wc = w & 3;       // 2M x 4N wave grid
  int lo = lane & 15, hi = lane >> 4;
  int xorv = (lo & 7) << 4;          // read-side XOR (row&7 == lo&7 everywhere)

  int srow = tid >> 3;               // 0..63 within region
  int gc = (tid & 7) ^ (srow & 7);
  const unsigned short* gA0 = encb + (size_t)(row0 + srow) * Hdim + gc * 8;
  const unsigned short* gB0 = W2b + (size_t)(np * SBN + srow) * Hdim + gc * 8;

  auto SA = [&](int g, int t, int s) {
    __builtin_amdgcn_global_load_lds(
        (const __attribute__((address_space(1))) unsigned int*)(gA0 + (size_t)g * 64 * Hdim + t * SBK),
        (__attribute__((address_space(3))) unsigned int*)(&As[s][(g * 512 + w * 64) * 8]), 16, 0, 0);
  };
  auto SB = [&](int g, int t, int s) {
    __builtin_amdgcn_global_load_lds(
        (const __attribute__((address_space(1))) unsigned int*)(gB0 + (size_t)g * 64 * Hdim + t * SBK),
        (__attribute__((address_space(3))) unsigned int*)(&Bs[s][(g * 512 + w * 64) * 8]), 16, 0, 0);
  };

  f32x4 acc[2][2][4][2] = {};  // [mh][nh][m][n]
  s16x8 af[2][4][2];           // [mh][m][ks] held across phases within a group
  s16x8 bf[2][2];              // [n][ks] reloaded per nh

  // prologue: tile 0 -> buffer 0 in the schedule's pair order
  SA(0, 0, 0); SB(0, 0, 0);
  SA(1, 0, 0); SB(1, 0, 0);
  SA(2, 0, 0); SA(3, 0, 0);
  SB(2, 0, 0); SB(3, 0, 0);
  asm volatile("s_waitcnt vmcnt(4)" ::: "memory");
  __builtin_amdgcn_s_barrier();
  asm volatile("" ::: "memory");

  for (int it = 0; it < 8; ++it) {
    int t1 = 2 * it + 1;
    int t2 = (it < 7) ? 2 * it + 2 : 15;  // tail: dummy re-stage keeps counts uniform
    #pragma unroll
    for (int p = 0; p < 8; ++p) {
      const int grp = p >> 2;            // 0: read d0, stage d1<-t1 ; 1: read d1, stage d0<-t2
      const int q = p & 3;               // snake: 0:(0,0) 1:(1,0) 2:(1,1) 3:(0,1)
      const int mh = (q == 0 || q == 3) ? 0 : 1;
      const int nh = q >> 1;
      const int rs = grp;
      const int ss = grp ^ 1;
      const int st = grp ? t2 : t1;

      if (q == 0)      { SA(0, st, ss); SB(0, st, ss); }
      else if (q == 1) { SA(1, st, ss); SB(1, st, ss); }
      else if (q == 2) { SA(2, st, ss); SA(3, st, ss); }
      else             { SB(2, st, ss); SB(3, st, ss); }

      const char* Ab = (const char*)As[rs];
      const char* Bb = (const char*)Bs[rs];
      if (q == 0 || q == 1) {  // load af[mh] (fresh mh-half)
        #pragma unroll
        for (int m = 0; m < 4; ++m)
          #pragma unroll
          for (int ks = 0; ks < 2; ++ks)
            af[mh][m][ks] = *reinterpret_cast<const s16x8*>(
                Ab + (mh * 128 + wr * 64 + m * 16 + lo) * 128 + ((ks * 64 + hi * 16) ^ xorv));
      }
      if (q == 0 || q == 2) {  // load bf for this nh (reused by the next phase)
        #pragma unroll
        for (int n = 0; n < 2; ++n)
          #pragma unroll
          for (int ks = 0; ks < 2; ++ks)
            bf[n][ks] = *reinterpret_cast<const s16x8*>(
                Bb + (nh * 128 + wc * 32 + n * 16 + lo) * 128 + ((ks * 64 + hi * 16) ^ xorv));
      }

      asm volatile("s_waitcnt vmcnt(4)" ::: "memory");
      __builtin_amdgcn_s_barrier();
      asm volatile("" ::: "memory");

      __builtin_amdgcn_s_setprio(1);
      #pragma unroll
      for (int ks = 0; ks < 2; ++ks)
        #pragma unroll
        for (int m = 0; m < 4; ++m)
          #pragma unroll
          for (int n = 0; n < 2; ++n)
            acc[mh][nh][m][n] = __builtin_amdgcn_mfma_f32_16x16x32_bf16(
                af[mh][m][ks], bf[n][ks], acc[mh][nh][m][n], 0, 0, 0);
      __builtin_amdgcn_s_setprio(0);
    }
  }

  // epilogue: fast tanh(energy + dh_proj)*v summed over this block's 256 o's
  float psum[2][4][4] = {};  // [mh][m][r]
  #pragma unroll
  for (int nh = 0; nh < 2; ++nh)
    #pragma unroll
    for (int n = 0; n < 2; ++n) {
      int o = np * SBN + nh * 128 + wc * 32 + n * 16 + lo;
      float dv = dhp[b * Hdim + o];
      float vv = v[o];
      float vv2 = 2.f * vv;
      #pragma unroll
      for (int mh = 0; mh < 2; ++mh)
        #pragma unroll
        for (int m = 0; m < 4; ++m)
          #pragma unroll
          for (int r = 0; r < 4; ++r) {
            float x = acc[mh][nh][m][n][r] + dv;
            float e2 = __builtin_amdgcn_exp2f(x * TANH_C);
            float rc = __builtin_amdgcn_rcpf(1.f + e2);
            psum[mh][m][r] += vv - vv2 * rc;  // v * tanh(x)
          }
    }
  #pragma unroll
  for (int mask = 1; mask < 16; mask <<= 1)
    #pragma unroll
    for (int mh = 0; mh < 2; ++mh)
      #pragma unroll
      for (int m = 0; m < 4; ++m)
        #pragma unroll
        for (int r = 0; r < 4; ++r)
          psum[mh][m][r] += __shfl_xor(psum[mh][m][r], mask, 64);
  if (lo == 0) {
    #pragma unroll
    for (int mh = 0; mh < 2; ++mh)
      #pragma unroll
      for (int m = 0; m < 4; ++m)
        #pragma unroll
        for (int r = 0; r < 4; ++r)
          atomicAdd(&scores[row0 + mh * 128 + wr * 64 + m * 16 + hi * 4 + r], psum[mh][m][r]);
  }
}

// ---------------- score kernel (fallback): reg-staged fp32 path ----------------
#define BKt 64

__global__ __launch_bounds__(256, 3) void score_kernel(
    const float* __restrict__ enc, const float* __restrict__ W2f,
    const unsigned short* __restrict__ W2b, const float* __restrict__ dhp,
    const float* __restrict__ v, float* __restrict__ scores, int use_bf) {
  __shared__ unsigned short As[64 * BKt];
  int tid = threadIdx.x;
  int bid = blockIdx.x;
  int f = (bid & 7) * 512 + (bid >> 3);
  int rg = f >> 2;
  int oc = f & 3;
  int row0 = rg * 64;
  int b = row0 >> 10;
  int w = tid >> 6, lane = tid & 63;
  int lo = lane & 15, hi = lane >> 4;
  int n0 = oc * 256 + w * 64;

  const unsigned short* pB[4];
  const float* pBf[4];
  #pragma unroll
  for (int n = 0; n < 4; ++n) {
    int o = n0 + n * 16 + lo;
    pB[n]  = W2b + (size_t)o * Hdim + hi * 8;
    pBf[n] = W2f + (size_t)o * Hdim + hi * 8;
  }

  f32x4 acc[4][4] = {};

  for (int t = 0; t < 16; ++t) {
    int k0 = t * BKt;
    __syncthreads();
    #pragma unroll
    for (int cc = 0; cc < 2; ++cc) {
      int c = tid + cc * 256;
      int row = c >> 3;
      int j = c & 7;
      const float4* p = reinterpret_cast<const float4*>(
          enc + (size_t)(row0 + row) * Hdim + k0 + j * 8);
      float4 a = p[0];
      float4 bb = p[1];
      union { unsigned short us[8]; u32x4 v4; } pk;
      pk.us[0] = f2bf(a.x);  pk.us[1] = f2bf(a.y);  pk.us[2] = f2bf(a.z);  pk.us[3] = f2bf(a.w);
      pk.us[4] = f2bf(bb.x); pk.us[5] = f2bf(bb.y); pk.us[6] = f2bf(bb.z); pk.us[7] = f2bf(bb.w);
      int idx = row * BKt + ((j * 8) ^ ((row & 7) << 3));
      *reinterpret_cast<u32x4*>(&As[idx]) = pk.v4;
    }
    __syncthreads();

    #pragma unroll
    for (int ks = 0; ks < 2; ++ks) {
      s16x8 bfrag[4];
      #pragma unroll
      for (int n = 0; n < 4; ++n) {
        if (use_bf) {
          bfrag[n] = *reinterpret_cast<const s16x8*>(pB[n] + ks * 32);
        } else {
          const float4* p = reinterpret_cast<const float4*>(pBf[n] + ks * 32);
          float4 a = p[0];
          float4 bb = p[1];
          union { unsigned short us[8]; s16x8 v4; } pk;
          pk.us[0] = f2bf(a.x);  pk.us[1] = f2bf(a.y);  pk.us[2] = f2bf(a.z);  pk.us[3] = f2bf(a.w);
          pk.us[4] = f2bf(bb.x); pk.us[5] = f2bf(bb.y); pk.us[6] = f2bf(bb.z); pk.us[7] = f2bf(bb.w);
          bfrag[n] = pk.v4;
        }
      }
      #pragma unroll
      for (int m = 0; m < 4; ++m) {
        int kk = ks * 32 + hi * 8;
        s16x8 afrag = *reinterpret_cast<const s16x8*>(
            &As[(m * 16 + lo) * BKt + (kk ^ ((lo & 7) << 3))]);
        #pragma unroll
        for (int n = 0; n < 4; ++n)
          acc[m][n] = __builtin_amdgcn_mfma_f32_16x16x32_bf16(afrag, bfrag[n], acc[m][n], 0, 0, 0);
      }
    }
    #pragma unroll
    for (int n = 0; n < 4; ++n) { pB[n] += BKt; pBf[n] += BKt; }
  }

  float psum[4][4] = {};
  #pragma unroll
  for (int n = 0; n < 4; ++n) {
    int o = n0 + n * 16 + lo;
    float dv = dhp[b * Hdim + o];
    float vv = v[o];
    float vv2 = 2.f * vv;
    #pragma unroll
    for (int m = 0; m < 4; ++m)
      #pragma unroll
      for (int r = 0; r < 4; ++r) {
        float x = acc[m][n][r] + dv;
        float e2 = __builtin_amdgcn_exp2f(x * TANH_C);
        float rc = __builtin_amdgcn_rcpf(1.f + e2);
        psum[m][r] += vv - vv2 * rc;
      }
  }
  #pragma unroll
  for (int mask = 1; mask < 16; mask <<= 1)
    #pragma unroll
    for (int m = 0; m < 4; ++m)
      #pragma unroll
      for (int r = 0; r < 4; ++r)
        psum[m][r] += __shfl_xor(psum[m][r], mask, 64);
  if (lo == 0) {
    #pragma unroll
    for (int m = 0; m < 4; ++m)
      #pragma unroll
      for (int r = 0; r < 4; ++r)
        atomicAdd(&scores[row0 + m * 16 + hi * 4 + r], psum[m][r]);
  }
}

// In-place softmax over S=1024 per batch row. Grid: 64 blocks x 256 threads.
__global__ __launch_bounds__(256, 1) void softmax_kernel(float* __restrict__ attn) {
  __shared__ float redm[4];
  __shared__ float reds[4];
  int b = blockIdx.x, tid = threadIdx.x;
  float4 x = *reinterpret_cast<float4*>(attn + b * Sdim + tid * 4);
  float m = fmaxf(fmaxf(x.x, x.y), fmaxf(x.z, x.w));
  #pragma unroll
  for (int mask = 1; mask < 64; mask <<= 1) m = fmaxf(m, __shfl_xor(m, mask, 64));
  if ((tid & 63) == 0) redm[tid >> 6] = m;
  __syncthreads();
  m = fmaxf(fmaxf(redm[0], redm[1]), fmaxf(redm[2], redm[3]));
  float4 e;
  e.x = expf(x.x - m); e.y = expf(x.y - m); e.z = expf(x.z - m); e.w = expf(x.w - m);
  float s = e.x + e.y + e.z + e.w;
  #pragma unroll
  for (int mask = 1; mask < 64; mask <<= 1) s += __shfl_xor(s, mask, 64);
  if ((tid & 63) == 0) reds[tid >> 6] = s;
  __syncthreads();
  s = reds[0] + reds[1] + reds[2] + reds[3];
  float inv = 1.f / s;
  e.x *= inv; e.y *= inv; e.z *= inv; e.w *= inv;
  *reinterpret_cast<float4*>(attn + b * Sdim + tid * 4) = e;
}

// context[b][h] = sum_s attn[b][s] * enc[b][s][h], bf16 enc path.
// Grid: 1024 blocks (64 b x 16 s-chunks of 64).
__global__ __launch_bounds__(256, 1) void context_bf_kernel(
    const unsigned short* __restrict__ encb, const float* __restrict__ attn,
    float* __restrict__ ctx) {
  int b = blockIdx.x >> 4;
  int chunk = blockIdx.x & 15;
  int tid = threadIdx.x;
  int h0 = tid * 4;
  const unsigned short* ebase = encb + ((size_t)(b * Sdim + chunk * 64)) * Hdim + h0;
  const float* abase = attn + b * Sdim + chunk * 64;
  float4 acc = {0.f, 0.f, 0.f, 0.f};
  #pragma unroll 4
  for (int s = 0; s < 64; ++s) {
    float wgt = abase[s];
    ushort4 ev = *reinterpret_cast<const ushort4*>(ebase + (size_t)s * Hdim);
    acc.x += wgt * bf2f(ev.x);
    acc.y += wgt * bf2f(ev.y);
    acc.z += wgt * bf2f(ev.z);
    acc.w += wgt * bf2f(ev.w);
  }
  float* c = ctx + b * Hdim + h0;
  atomicAdd(c + 0, acc.x);
  atomicAdd(c + 1, acc.y);
  atomicAdd(c + 2, acc.z);
  atomicAdd(c + 3, acc.w);
}

// fp32 fallback context. Grid: 512 blocks (64 b x 8 s-chunks of 128).
__global__ __launch_bounds__(256, 1) void context_kernel(
    const float* __restrict__ enc, const float* __restrict__ attn,
    float* __restrict__ ctx) {
  int b = blockIdx.x >> 3;
  int chunk = blockIdx.x & 7;
  int tid = threadIdx.x;
  int h0 = tid * 4;
  const float* ebase = enc + ((size_t)(b * Sdim + chunk * 128)) * Hdim + h0;
  const float* abase = attn + b * Sdim + chunk * 128;
  float4 acc = {0.f, 0.f, 0.f, 0.f};
  #pragma unroll 4
  for (int s = 0; s < 128; ++s) {
    float wgt = abase[s];
    float4 ev = *reinterpret_cast<const float4*>(ebase + (size_t)s * Hdim);
    acc.x += wgt * ev.x; acc.y += wgt * ev.y; acc.z += wgt * ev.z; acc.w += wgt * ev.w;
  }
  float* c = ctx + b * Hdim + h0;
  atomicAdd(c + 0, acc.x);
  atomicAdd(c + 1, acc.y);
  atomicAdd(c + 2, acc.z);
  atomicAdd(c + 3, acc.w);
}

extern "C" void kernel_launch(void* const* d_in, const int* in_sizes, int n_in,
                              void* d_out, int out_size, void* d_ws, size_t ws_size,
                              hipStream_t stream) {
  const float* dh  = (const float*)d_in[0];  // [64,1024]
  const float* enc = (const float*)d_in[1];  // [64,1024,1024]
  const float* W1  = (const float*)d_in[2];  // [1024,1024]
  const float* W2  = (const float*)d_in[3];  // [1024,1024]
  const float* v   = (const float*)d_in[4];  // [1024]
  float* out_ctx  = (float*)d_out;           // [64,1024]
  float* out_attn = out_ctx + Bdim * Hdim;   // [64,1024]

  int use_bf = (ws_size >= 4ull * 1024 * 1024) ? 1 : 0;
  // fast path needs W1b+W2b (4 MB) + encb (128 MB)
  int big_ws = (ws_size >= 133ull * 1024 * 1024) ? 1 : 0;
  unsigned short* W1b  = (unsigned short*)d_ws;
  unsigned short* W2b  = W1b + 1024 * 1024;
  unsigned short* encb = W2b + 1024 * 1024;

  if (use_bf) {
    cast_bf16_kernel<<<512, 256, 0, stream>>>(W1, W1b);
    cast_bf16_kernel<<<512, 256, 0, stream>>>(W2, W2b);
  }
  if (big_ws) {
    cast_bf16_kernel<<<32768, 256, 0, stream>>>(enc, encb);
  }

  // dh_proj parked in out_ctx (region is free until the context pass)
  proj_kernel<<<64, 256, 0, stream>>>(dh, W1, W1b, out_ctx, use_bf);

  // raw scores accumulate into zeroed out_attn
  hipMemsetAsync(out_attn, 0, (size_t)Bdim * Sdim * sizeof(float), stream);
  if (big_ws) {
    score_mfma_kernel<<<1024, 512, 0, stream>>>(encb, W2b, out_ctx, v, out_attn);
  } else {
    score_kernel<<<4096, 256, 0, stream>>>(enc, W2, W2b, out_ctx, v, out_attn, use_bf);
  }

  softmax_kernel<<<Bdim, 256, 0, stream>>>(out_attn);

  hipMemsetAsync(out_ctx, 0, (size_t)Bdim * Hdim * sizeof(float), stream);
  if (big_ws) {
    context_bf_kernel<<<1024, 256, 0, stream>>>(encb, out_attn, out_ctx);
  } else {
    context_kernel<<<512, 256, 0, stream>>>(enc, out_attn, out_ctx);
  }
}